// Round 10
// baseline (251.667 us; speedup 1.0000x reference)
//
#include <hip/hip_runtime.h>
#include <hip/hip_fp8.h>
#include <math.h>

#define NB 8
#define CI 512
#define CO 256
#define NN 2048           // T*H*W
#define SCALE 0.0625f     // 1/sqrt(CO), applied inside exp in attention
#define SPLIT 4           // KV split factor

typedef __bf16 v8bf __attribute__((ext_vector_type(8)));
typedef __bf16 v4bf __attribute__((ext_vector_type(4)));
typedef float  f32x4  __attribute__((ext_vector_type(4)));
typedef float  f32x16 __attribute__((ext_vector_type(16)));
typedef unsigned char u8;
typedef long i64t;

static __device__ __forceinline__ u8 to_fp8(float x) {
    __hip_fp8_e4m3 t(x);           // OCP e4m3fn on gfx950
    return (u8)t.__x;
}

static __device__ __forceinline__ i64t pack64(unsigned lo, unsigned hi) {
    return (i64t)(((unsigned long long)hi << 32) | (unsigned long long)lo);
}

// ---------------------------------------------------------------------------
// Fused projections v5: round-1 geometry (128n x 64co, BK=32, 24 MFMA/chunk,
// grid 512) with ONE change: staging loads fully hoisted WITHIN the chunk.
// Evidence (r9, BK-64): per-chunk time superlinear in staging-inst count ->
// chunk cost = (#load-latency windows) x ~700cyc. Round-1 interleaved each
// 8-load group with its LDS write (waitcnt every 8 loads = ~5 windows).
// v5 issues all 38 VMEM first (results in regs, live only within staging,
// NOT across the barrier - r4's mistake), then cvt+write, then barrier.
// History: BK-64 90us (r9), reg-prefetch-across-barrier 56.6us (r4),
// 64x64 tile 67.4us (r3), baseline 43.5us (r1/r5).
// ---------------------------------------------------------------------------
__global__ __launch_bounds__(256, 2)
void proj3_kernel(const float* __restrict__ x, const float* __restrict__ query,
                  const float* __restrict__ wk, const float* __restrict__ bk,
                  const float* __restrict__ wv, const float* __restrict__ bv,
                  const float* __restrict__ wq, const float* __restrict__ bq,
                  u8* __restrict__ outK, u8* __restrict__ outV, u8* __restrict__ outQ)
{
    const int b = blockIdx.z, n0 = blockIdx.x * 128, co0 = blockIdx.y * 64;
    const int tid = threadIdx.x;
    const int wave = tid >> 6, lane = tid & 63;
    const int l16 = lane & 15, quad = lane >> 4;
    const int wn = wave & 1, wc = wave >> 1;

    __shared__ __bf16 Xt[128][40];
    __shared__ __bf16 Qt[128][40];
    __shared__ __bf16 Wks[64][40];
    __shared__ __bf16 Wvs[64][40];
    __shared__ __bf16 Wqs[64][40];

    const float* xb = x + (size_t)b * CI * NN;
    const float* qb = query + (size_t)b * CI * NN;

    f32x4 acck[4][2], accv[2][4], accq[4][2];
    #pragma unroll
    for (int i = 0; i < 4; ++i)
        #pragma unroll
        for (int j = 0; j < 2; ++j) {
            acck[i][j] = f32x4{0,0,0,0}; accv[j][i] = f32x4{0,0,0,0};
            accq[i][j] = f32x4{0,0,0,0};
        }

    const int xn = tid & 127;
    const int xc = tid >> 7;
    const int wco = tid >> 3, wcq = tid & 7;   // weight coords (g adds +32 rows)

    for (int k0 = 0; k0 < CI; k0 += 32) {
        // ---- phase 1: issue ALL staging loads (one latency window) ----
        float xr[2][8], qr[2][8];
        float4 wa[2], wcv[2], wqv[2];
        #pragma unroll
        for (int g = 0; g < 2; ++g) {
            const int cg = xc + g * 2;
            #pragma unroll
            for (int j = 0; j < 8; ++j) {
                xr[g][j] = xb[(size_t)(k0 + cg * 8 + j) * NN + n0 + xn];
                qr[g][j] = qb[(size_t)(k0 + cg * 8 + j) * NN + n0 + xn];
            }
        }
        #pragma unroll
        for (int g = 0; g < 2; ++g) {
            const int co = wco + g * 32;
            wa[g]  = *(const float4*)(wk + (size_t)(co0 + co) * CI + k0 + wcq * 4);
            wcv[g] = *(const float4*)(wv + (size_t)(co0 + co) * CI + k0 + wcq * 4);
            wqv[g] = *(const float4*)(wq + (size_t)(co0 + co) * CI + k0 + wcq * 4);
        }
        // ---- phase 2: convert + write LDS ----
        #pragma unroll
        for (int g = 0; g < 2; ++g) {
            const int cg = xc + g * 2;
            v8bf z, w;
            #pragma unroll
            for (int j = 0; j < 8; ++j) { z[j] = (__bf16)xr[g][j]; w[j] = (__bf16)qr[g][j]; }
            *(v8bf*)&Xt[xn][cg * 8] = z;
            *(v8bf*)&Qt[xn][cg * 8] = w;
        }
        #pragma unroll
        for (int g = 0; g < 2; ++g) {
            const int co = wco + g * 32;
            *(v4bf*)&Wks[co][wcq * 4] = v4bf{(__bf16)wa[g].x,  (__bf16)wa[g].y,  (__bf16)wa[g].z,  (__bf16)wa[g].w};
            *(v4bf*)&Wvs[co][wcq * 4] = v4bf{(__bf16)wcv[g].x, (__bf16)wcv[g].y, (__bf16)wcv[g].z, (__bf16)wcv[g].w};
            *(v4bf*)&Wqs[co][wcq * 4] = v4bf{(__bf16)wqv[g].x, (__bf16)wqv[g].y, (__bf16)wqv[g].z, (__bf16)wqv[g].w};
        }
        __syncthreads();
        // ---- phase 3: fragments + MFMA ----
        v8bf ax[4], aqx[4], bkf[2], bqf[2];
        #pragma unroll
        for (int i = 0; i < 4; ++i) {
            ax[i]  = *(const v8bf*)&Xt[wn * 64 + i * 16 + l16][quad * 8];
            aqx[i] = *(const v8bf*)&Qt[wn * 64 + i * 16 + l16][quad * 8];
        }
        #pragma unroll
        for (int j = 0; j < 2; ++j) {
            bkf[j] = *(const v8bf*)&Wks[wc * 32 + j * 16 + l16][quad * 8];
            bqf[j] = *(const v8bf*)&Wqs[wc * 32 + j * 16 + l16][quad * 8];
        }
        __builtin_amdgcn_s_setprio(1);
        #pragma unroll
        for (int i = 0; i < 4; ++i)
            #pragma unroll
            for (int j = 0; j < 2; ++j) {
                acck[i][j] = __builtin_amdgcn_mfma_f32_16x16x32_bf16(ax[i],  bkf[j], acck[i][j], 0, 0, 0);
                accq[i][j] = __builtin_amdgcn_mfma_f32_16x16x32_bf16(aqx[i], bqf[j], accq[i][j], 0, 0, 0);
            }
        {
            v8bf avf[2];
            #pragma unroll
            for (int j = 0; j < 2; ++j) avf[j] = *(const v8bf*)&Wvs[wc * 32 + j * 16 + l16][quad * 8];
            #pragma unroll
            for (int j = 0; j < 2; ++j)
                #pragma unroll
                for (int i = 0; i < 4; ++i)
                    accv[j][i] = __builtin_amdgcn_mfma_f32_16x16x32_bf16(avf[j], ax[i], accv[j][i], 0, 0, 0);
        }
        __builtin_amdgcn_s_setprio(0);
        __syncthreads();
    }
    // k and q epilogues: D[m=n][col=co], fp8 out
    #pragma unroll
    for (int i = 0; i < 4; ++i) {
        int n = n0 + wn * 64 + i * 16 + quad * 4;
        #pragma unroll
        for (int j = 0; j < 2; ++j) {
            int co = co0 + wc * 32 + j * 16 + l16;
            float bkk = bk[co], bqq = bq[co];
            u8* dk = outK + ((size_t)b * NN + n) * CO + co;
            u8* dq = outQ + ((size_t)b * NN + n) * CO + co;
            #pragma unroll
            for (int r = 0; r < 4; ++r) {
                dk[(size_t)r * CO] = to_fp8(acck[i][j][r] + bkk);
                dq[(size_t)r * CO] = to_fp8(accq[i][j][r] + bqq);
            }
        }
    }
    // v epilogue: D[m=co][col=n]
    #pragma unroll
    for (int j = 0; j < 2; ++j) {
        int co = co0 + wc * 32 + j * 16 + quad * 4;
        #pragma unroll
        for (int r = 0; r < 4; ++r) {
            float bvv = bv[co + r];
            #pragma unroll
            for (int i = 0; i < 4; ++i) {
                int n = n0 + wn * 64 + i * 16 + l16;
                outV[((size_t)b * CO + co + r) * NN + n] = to_fp8(accv[j][i][r] + bvv);
            }
        }
    }
}

// ---------------------------------------------------------------------------
// Flash attention v2: swapped-operand QK^T (D[kv][q]) keeps each lane's full
// P row in registers -> in-register fp8 pack (cvt_pk_fp8) feeds PV's A-frag
// DIRECTLY (k-slot permutation absorbed into the V LDS dword order at staging:
// middle-dword swap). No duplicated QK^T, no P LDS round-trip, no cross-lane.
// Each wave: 32 q-rows x full Co=256 (acc 8x f32x16 = 128 VGPR). Block = 128q,
// 4 waves. LDS qword-padded: Ks pitch 264B / Vt pitch 72B -> 2-way max (free).
// T14 async stage split (issue global loads under compute), T5 setprio.
// ---------------------------------------------------------------------------
__global__ __launch_bounds__(256, 2)
void attn_kernel(const u8* __restrict__ kT, const u8* __restrict__ qT,
                 const u8* __restrict__ vT2, __bf16* __restrict__ Opart,
                 float* __restrict__ lbuf)
{
    const int b = blockIdx.z, part = blockIdx.y, n0 = blockIdx.x * 128;
    const int tid = threadIdx.x;
    const int wave = tid >> 6, lane = tid & 63;
    const int l32 = lane & 31, hs = lane >> 5;

    __shared__ i64t Ks8[64][33];    // [kv][c qwords], pitch 264 B (66 dw: 2-way)
    __shared__ i64t Vt8[256][9];    // [co][kv qwords, dword-interleaved], 72 B

    const int start = part * (NN / SPLIT);        // 512 kv per part
    const u8* Ksrc = qT + ((size_t)b * NN + start) * CO;   // attn-K rows [kv][c]
    const u8* Vsrc = vT2 + (size_t)b * CO * NN + start;    // [co][kv]

    // resident Q fragments (B operand): lane holds Q[q=l32][c=s*16+hs*8 ..+7]
    i64t aq[16];
    {
        const u8* qrow = kT + ((size_t)b * NN + n0 + wave * 32 + l32) * CO + hs * 8;
        #pragma unroll
        for (int s = 0; s < 16; ++s) aq[s] = *(const i64t*)(qrow + s * 16);
    }

    f32x16 acc[8];
    #pragma unroll
    for (int t = 0; t < 8; ++t)
        #pragma unroll
        for (int r = 0; r < 16; ++r) acc[t][r] = 0.f;
    float lp = 0.f;

    // T14: stage tile 0 into registers
    int4 kx[4], vx[4];
    #pragma unroll
    for (int r2 = 0; r2 < 4; ++r2) {
        int c = tid + 256 * r2;
        kx[r2] = *(const int4*)(Ksrc + (size_t)(c >> 4) * CO + (c & 15) * 16);
        vx[r2] = *(const int4*)(Vsrc + (size_t)(c >> 2) * NN + (c & 3) * 16);
    }

    for (int it = 0; it < NN / SPLIT / 64; ++it) {
        // registers -> LDS (split b64 writes; V gets middle-dword swap so that
        // row qword 2g   = kv{16g+0..3, 16g+8..11}  (PV slots 0-7,  hs=0)
        //     qword 2g+1 = kv{16g+4..7, 16g+12..15} (PV slots 8-15, hs=1)
        #pragma unroll
        for (int r2 = 0; r2 < 4; ++r2) {
            int c = tid + 256 * r2;
            i64t* kd = &Ks8[c >> 4][(c & 15) * 2];
            kd[0] = *(const i64t*)&kx[r2].x;
            kd[1] = *(const i64t*)&kx[r2].z;
            i64t* vd = &Vt8[c >> 2][(c & 3) * 2];
            vd[0] = pack64((unsigned)vx[r2].x, (unsigned)vx[r2].z);
            vd[1] = pack64((unsigned)vx[r2].y, (unsigned)vx[r2].w);
        }
        __syncthreads();

        // issue next tile's global loads; latency hides under QK^T + PV
        if (it + 1 < NN / SPLIT / 64) {
            const u8* Kit = Ksrc + (size_t)(it + 1) * 64 * CO;
            const u8* Vit = Vsrc + (it + 1) * 64;
            #pragma unroll
            for (int r2 = 0; r2 < 4; ++r2) {
                int c = tid + 256 * r2;
                kx[r2] = *(const int4*)(Kit + (size_t)(c >> 4) * CO + (c & 15) * 16);
                vx[r2] = *(const int4*)(Vit + (size_t)(c >> 2) * NN + (c & 3) * 16);
            }
        }

        // S^T = K Q^T per 32-kv subtile: D[kv][q=l32]; softmax lane-local
        int dpk[8];
        #pragma unroll
        for (int sub = 0; sub < 2; ++sub) {
            f32x16 sacc;
            #pragma unroll
            for (int r = 0; r < 16; ++r) sacc[r] = 0.f;
            __builtin_amdgcn_s_setprio(1);
            #pragma unroll
            for (int s = 0; s < 16; ++s) {
                i64t kf = Ks8[sub * 32 + l32][s * 2 + hs];
                sacc = __builtin_amdgcn_mfma_f32_32x32x16_fp8_fp8(kf, aq[s], sacc, 0, 0, 0);
            }
            __builtin_amdgcn_s_setprio(0);
            // stats-free softmax: p = exp(S/16); reg r -> kv = (r&3)+8*(r>>2)+4*hs
            #pragma unroll
            for (int r = 0; r < 16; ++r) {
                sacc[r] = __expf(sacc[r] * SCALE);
                lp += sacc[r];
            }
            #pragma unroll
            for (int g = 0; g < 4; ++g) {
                int lo = __builtin_amdgcn_cvt_pk_fp8_f32(sacc[4*g+0], sacc[4*g+1], 0, false);
                dpk[sub * 4 + g] = __builtin_amdgcn_cvt_pk_fp8_f32(sacc[4*g+2], sacc[4*g+3], lo, true);
            }
        }
        // PV A-frags: chunk c (16 kv) = {dpk[2c], dpk[2c+1]} — already slot-ordered
        i64t pa[4];
        #pragma unroll
        for (int c = 0; c < 4; ++c)
            pa[c] = pack64((unsigned)dpk[2 * c], (unsigned)dpk[2 * c + 1]);

        __builtin_amdgcn_s_setprio(1);
        #pragma unroll
        for (int t = 0; t < 8; ++t) {
            #pragma unroll
            for (int c = 0; c < 4; ++c) {
                i64t bvf = Vt8[t * 32 + l32][c * 2 + hs];
                acc[t] = __builtin_amdgcn_mfma_f32_32x32x16_fp8_fp8(pa[c], bvf, acc[t], 0, 0, 0);
            }
        }
        __builtin_amdgcn_s_setprio(0);
        __syncthreads();   // LDS reads done before next tile's writes
    }

    // row sums: lane holds half of q-row l32's kv mass; partner is lane^32
    lp += __shfl_xor(lp, 32);
    if (hs == 0)
        lbuf[(size_t)(part * NB + b) * NN + n0 + wave * 32 + l32] = lp;

    // store unnormalized bf16 partial: D[q over regs][co = t*32 + l32]
    const size_t qbase = (size_t)(part * NB + b) * NN + n0 + wave * 32;
    #pragma unroll
    for (int t = 0; t < 8; ++t)
        #pragma unroll
        for (int r = 0; r < 16; ++r) {
            int row = (r & 3) + 8 * (r >> 2) + 4 * hs;
            Opart[(qbase + row) * CO + t * 32 + l32] = (__bf16)acc[t][r];
        }
}

// ---------------------------------------------------------------------------
// up v3: merge fused into staging. out[b][ci][n] = x + sc*(b2[ci] +
// sum_cv w2[ci][cv] * Z'[cv][n]) where Z'[cv][n] = (sum_p Opart_p)/(sum_p l_p)
// viewed through the raw [B,N,Co]->[B,Co,N] reshape. For a fixed block the
// softmax row n_orig = cv*8 + (n0>>8) (constant across each 8-elem run and
// across the 128-n tile), so a 256-entry LDS invl table indexed by cv covers
// all chunks. Eliminates merge_kernel (40 MB pass + launch) and the ob buffer;
// arithmetic identical minus one bf16 round-trip.
// ---------------------------------------------------------------------------
__global__ __launch_bounds__(256)
void up_kernel(const __bf16* __restrict__ Opart, const float* __restrict__ lbuf,
               const float* __restrict__ x,
               const float* __restrict__ w2, const float* __restrict__ b2,
               const float* __restrict__ scaling, float* __restrict__ out)
{
    const int b = blockIdx.z, n0 = blockIdx.x * 128, ci0 = blockIdx.y * 128;
    const int tid = threadIdx.x;
    const int wave = tid >> 6, lane = tid & 63;
    const int l16 = lane & 15, quad = lane >> 4;
    const int wn = wave & 1, wci = wave >> 1;

    __shared__ __bf16 Zt[128][40];
    __shared__ __bf16 Wt[128][40];
    __shared__ float invl[256];

    const size_t PSTRIDE = (size_t)NB * NN * CO;            // Opart part stride
    const __bf16* Opb = Opart + (size_t)b * NN * CO;        // this batch, part 0

    // per-block denominator table: invl[cv] = 1 / sum_p l_p[cv*8 + (n0>>8)]
    {
        const int norig = tid * 8 + (n0 >> 8);
        float ls = 0.f;
        #pragma unroll
        for (int p = 0; p < SPLIT; ++p)
            ls += lbuf[(size_t)(p * NB + b) * NN + norig];
        invl[tid] = 1.0f / ls;
    }
    __syncthreads();

    f32x4 acc[4][4];
    #pragma unroll
    for (int i = 0; i < 4; ++i)
        #pragma unroll
        for (int j = 0; j < 4; ++j) acc[i][j] = f32x4{0,0,0,0};

    // Z staging coords: thread owns 8 consecutive n (one row-stripe) x 1 cv,
    // two units (cv and cv+16). Stripe zm = row>>3, thread-constant.
    const int zm = tid & 15;          // n-stripe: rows zm*8 .. zm*8+7
    const int zcv = tid >> 4;         // cv lane 0..15
    const int zsw = 8 * (zm & 3);     // XOR column swizzle (thread-constant)

    for (int k0 = 0; k0 < CO; k0 += 32) {
        #pragma unroll
        for (int u = 0; u < 2; ++u) {
            const int cv = zcv + 16 * u;
            const size_t fbase = (size_t)(k0 + cv) * NN + n0 + zm * 8;
            float s[8] = {0,0,0,0,0,0,0,0};
            #pragma unroll
            for (int p = 0; p < SPLIT; ++p) {
                v8bf v = *(const v8bf*)(Opb + (size_t)p * PSTRIDE + fbase);
                #pragma unroll
                for (int j = 0; j < 8; ++j) s[j] += (float)v[j];
            }
            const float il = invl[k0 + cv];
            const int col = cv ^ zsw;
            #pragma unroll
            for (int i = 0; i < 8; ++i)
                Zt[zm * 8 + i][col] = (__bf16)(s[i] * il);
        }
        #pragma unroll
        for (int g = 0; g < 4; ++g) {
            int f = tid + 256 * g;
            int ci = f >> 3, cq = f & 7;
            float4 v = *(const float4*)(w2 + (size_t)(ci0 + ci) * CO + k0 + cq * 4);
            *(v4bf*)&Wt[ci][cq * 4] = v4bf{(__bf16)v.x, (__bf16)v.y, (__bf16)v.z, (__bf16)v.w};
        }
        __syncthreads();
        v8bf aw[4], bz[4];
        #pragma unroll
        for (int i = 0; i < 4; ++i) aw[i] = *(const v8bf*)&Wt[wci * 64 + i * 16 + l16][quad * 8];
        #pragma unroll
        for (int j = 0; j < 4; ++j) {
            const int row = wn * 64 + j * 16 + l16;
            const int col = (quad ^ ((row >> 3) & 3)) * 8;   // inverse swizzle
            bz[j] = *(const v8bf*)&Zt[row][col];
        }
        #pragma unroll
        for (int i = 0; i < 4; ++i)
            #pragma unroll
            for (int j = 0; j < 4; ++j)
                acc[i][j] = __builtin_amdgcn_mfma_f32_16x16x32_bf16(aw[i], bz[j], acc[i][j], 0, 0, 0);
        __syncthreads();
    }
    float sc = scaling[0];
    #pragma unroll
    for (int i = 0; i < 4; ++i) {
        int ci = ci0 + wci * 64 + i * 16 + quad * 4;
        #pragma unroll
        for (int r = 0; r < 4; ++r) {
            float bvv = b2[ci + r];
            #pragma unroll
            for (int j = 0; j < 4; ++j) {
                int n = n0 + wn * 64 + j * 16 + l16;
                size_t gi = ((size_t)b * CI + ci + r) * NN + n;
                out[gi] = x[gi] + sc * (acc[i][j][r] + bvv);
            }
        }
    }
}

extern "C" void kernel_launch(void* const* d_in, const int* in_sizes, int n_in,
                              void* d_out, int out_size, void* d_ws, size_t ws_size,
                              hipStream_t stream)
{
    (void)in_sizes; (void)n_in; (void)out_size; (void)ws_size;
    const float* x       = (const float*)d_in[0];
    const float* query   = (const float*)d_in[1];
    const float* key_w   = (const float*)d_in[2];
    const float* key_b   = (const float*)d_in[3];
    const float* val_w   = (const float*)d_in[4];
    const float* val_b   = (const float*)d_in[5];
    const float* query_w = (const float*)d_in[6];
    const float* query_b = (const float*)d_in[7];
    const float* up_w    = (const float*)d_in[8];
    const float* up_b    = (const float*)d_in[9];
    const float* scaling = (const float*)d_in[10];
    float* out = (float*)d_out;

    const size_t TEN = (size_t)NB * NN * CO;   // 4,194,304 elements
    u8* kT  = (u8*)d_ws;                       // [B,N,Co] fp8 (key proj = attn Q)
    u8* qT  = kT + TEN;                        // [B,N,Co] fp8 (query proj = attn K)
    u8* vT2 = qT + TEN;                        // [B,Co,N] fp8
    __bf16* Opart = (__bf16*)(vT2 + TEN);      // [SPLIT,B,N,Co] bf16
    float*  lbuf  = (float*)(Opart + (size_t)SPLIT * TEN);  // [SPLIT,B,N]

    dim3 blk(256);
    proj3_kernel<<<dim3(NN / 128, CO / 64, NB), blk, 0, stream>>>(
        x, query, key_w, key_b, val_w, val_b, query_w, query_b, kT, vT2, qT);
    attn_kernel<<<dim3(NN / 128, SPLIT, NB), blk, 0, stream>>>(kT, qT, vT2, Opart, lbuf);
    up_kernel<<<dim3(NN / 128, CI / 128, NB), blk, 0, stream>>>(
        Opart, lbuf, x, up_w, up_b, scaling, out);
}

// Round 11
// 204.379 us; speedup vs baseline: 1.2314x; 1.2314x over previous
//
#include <hip/hip_runtime.h>
#include <hip/hip_fp8.h>
#include <math.h>

#define NB 8
#define CI 512
#define CO 256
#define NN 2048           // T*H*W
#define SCALE 0.0625f     // 1/sqrt(CO), applied inside exp in attention
#define SPLIT 4           // KV split factor

typedef __bf16 v8bf __attribute__((ext_vector_type(8)));
typedef __bf16 v4bf __attribute__((ext_vector_type(4)));
typedef float  f32x4  __attribute__((ext_vector_type(4)));
typedef float  f32x16 __attribute__((ext_vector_type(16)));
typedef unsigned char u8;
typedef long i64t;

static __device__ __forceinline__ u8 to_fp8(float x) {
    __hip_fp8_e4m3 t(x);           // OCP e4m3fn on gfx950
    return (u8)t.__x;
}

static __device__ __forceinline__ i64t pack64(unsigned lo, unsigned hi) {
    return (i64t)(((unsigned long long)hi << 32) | (unsigned long long)lo);
}

// ---------------------------------------------------------------------------
// Fused projections (round-1 proven structure, 43.5 us): k = key_w@x
// (fp8 [B,N,Co]), v = val_w@x (fp8 [B,Co,N]), q = query_w@query (fp8 [B,N,Co]).
// Tile 128n x 64co, K-chunk 32, bf16 MFMA. Direct load->cvt->LDS staging.
// SCHEDULING INTERVENTIONS ALL MEASURED SLOWER - do not redo:
//   r3 64x64 tile: 67.4us | r4 cross-barrier prefetch: 56.6us
//   r9 BK=64: 90us        | r10 in-chunk load hoist: 96us (VGPR 96, serialized)
// hipcc's in-phase scheduling of this interleaved pattern is the optimum
// found; residual stall is structural (2 waves/SIMD, grid-capped).
// ---------------------------------------------------------------------------
__global__ __launch_bounds__(256, 2)
void proj3_kernel(const float* __restrict__ x, const float* __restrict__ query,
                  const float* __restrict__ wk, const float* __restrict__ bk,
                  const float* __restrict__ wv, const float* __restrict__ bv,
                  const float* __restrict__ wq, const float* __restrict__ bq,
                  u8* __restrict__ outK, u8* __restrict__ outV, u8* __restrict__ outQ)
{
    const int b = blockIdx.z, n0 = blockIdx.x * 128, co0 = blockIdx.y * 64;
    const int tid = threadIdx.x;
    const int wave = tid >> 6, lane = tid & 63;
    const int l16 = lane & 15, quad = lane >> 4;
    const int wn = wave & 1, wc = wave >> 1;

    __shared__ __bf16 Xt[128][40];
    __shared__ __bf16 Qt[128][40];
    __shared__ __bf16 Wks[64][40];
    __shared__ __bf16 Wvs[64][40];
    __shared__ __bf16 Wqs[64][40];

    const float* xb = x + (size_t)b * CI * NN;
    const float* qb = query + (size_t)b * CI * NN;

    f32x4 acck[4][2], accv[2][4], accq[4][2];
    #pragma unroll
    for (int i = 0; i < 4; ++i)
        #pragma unroll
        for (int j = 0; j < 2; ++j) {
            acck[i][j] = f32x4{0,0,0,0}; accv[j][i] = f32x4{0,0,0,0};
            accq[i][j] = f32x4{0,0,0,0};
        }

    const int xn = tid & 127;
    const int xc = tid >> 7;

    for (int k0 = 0; k0 < CI; k0 += 32) {
        #pragma unroll
        for (int g = 0; g < 2; ++g) {
            int cg = xc + g * 2;
            v8bf z, w;
            #pragma unroll
            for (int j = 0; j < 8; ++j) {
                z[j] = (__bf16)xb[(size_t)(k0 + cg * 8 + j) * NN + n0 + xn];
                w[j] = (__bf16)qb[(size_t)(k0 + cg * 8 + j) * NN + n0 + xn];
            }
            *(v8bf*)&Xt[xn][cg * 8] = z;
            *(v8bf*)&Qt[xn][cg * 8] = w;
        }
        #pragma unroll
        for (int g = 0; g < 2; ++g) {
            int f = tid + 256 * g;
            int co = f >> 3, cq = f & 7;
            float4 a = *(const float4*)(wk + (size_t)(co0 + co) * CI + k0 + cq * 4);
            float4 c = *(const float4*)(wv + (size_t)(co0 + co) * CI + k0 + cq * 4);
            float4 d = *(const float4*)(wq + (size_t)(co0 + co) * CI + k0 + cq * 4);
            *(v4bf*)&Wks[co][cq * 4] = v4bf{(__bf16)a.x, (__bf16)a.y, (__bf16)a.z, (__bf16)a.w};
            *(v4bf*)&Wvs[co][cq * 4] = v4bf{(__bf16)c.x, (__bf16)c.y, (__bf16)c.z, (__bf16)c.w};
            *(v4bf*)&Wqs[co][cq * 4] = v4bf{(__bf16)d.x, (__bf16)d.y, (__bf16)d.z, (__bf16)d.w};
        }
        __syncthreads();
        v8bf ax[4], aqx[4], bkf[2], bqf[2];
        #pragma unroll
        for (int i = 0; i < 4; ++i) {
            ax[i]  = *(const v8bf*)&Xt[wn * 64 + i * 16 + l16][quad * 8];
            aqx[i] = *(const v8bf*)&Qt[wn * 64 + i * 16 + l16][quad * 8];
        }
        #pragma unroll
        for (int j = 0; j < 2; ++j) {
            bkf[j] = *(const v8bf*)&Wks[wc * 32 + j * 16 + l16][quad * 8];
            bqf[j] = *(const v8bf*)&Wqs[wc * 32 + j * 16 + l16][quad * 8];
        }
        #pragma unroll
        for (int i = 0; i < 4; ++i)
            #pragma unroll
            for (int j = 0; j < 2; ++j) {
                acck[i][j] = __builtin_amdgcn_mfma_f32_16x16x32_bf16(ax[i],  bkf[j], acck[i][j], 0, 0, 0);
                accq[i][j] = __builtin_amdgcn_mfma_f32_16x16x32_bf16(aqx[i], bqf[j], accq[i][j], 0, 0, 0);
            }
        {
            v8bf avf[2];
            #pragma unroll
            for (int j = 0; j < 2; ++j) avf[j] = *(const v8bf*)&Wvs[wc * 32 + j * 16 + l16][quad * 8];
            #pragma unroll
            for (int j = 0; j < 2; ++j)
                #pragma unroll
                for (int i = 0; i < 4; ++i)
                    accv[j][i] = __builtin_amdgcn_mfma_f32_16x16x32_bf16(avf[j], ax[i], accv[j][i], 0, 0, 0);
        }
        __syncthreads();
    }
    // k and q epilogues: D[m=n][col=co], fp8 out
    #pragma unroll
    for (int i = 0; i < 4; ++i) {
        int n = n0 + wn * 64 + i * 16 + quad * 4;
        #pragma unroll
        for (int j = 0; j < 2; ++j) {
            int co = co0 + wc * 32 + j * 16 + l16;
            float bkk = bk[co], bqq = bq[co];
            u8* dk = outK + ((size_t)b * NN + n) * CO + co;
            u8* dq = outQ + ((size_t)b * NN + n) * CO + co;
            #pragma unroll
            for (int r = 0; r < 4; ++r) {
                dk[(size_t)r * CO] = to_fp8(acck[i][j][r] + bkk);
                dq[(size_t)r * CO] = to_fp8(accq[i][j][r] + bqq);
            }
        }
    }
    // v epilogue: D[m=co][col=n]
    #pragma unroll
    for (int j = 0; j < 2; ++j) {
        int co = co0 + wc * 32 + j * 16 + quad * 4;
        #pragma unroll
        for (int r = 0; r < 4; ++r) {
            float bvv = bv[co + r];
            #pragma unroll
            for (int i = 0; i < 4; ++i) {
                int n = n0 + wn * 64 + i * 16 + l16;
                outV[((size_t)b * CO + co + r) * NN + n] = to_fp8(accv[j][i][r] + bvv);
            }
        }
    }
}

// ---------------------------------------------------------------------------
// Flash attention v2: swapped-operand QK^T (D[kv][q]) keeps each lane's full
// P row in registers -> in-register fp8 pack (cvt_pk_fp8) feeds PV's A-frag
// DIRECTLY (k-slot permutation absorbed into the V LDS dword order at staging:
// middle-dword swap). No duplicated QK^T, no P LDS round-trip, no cross-lane.
// Each wave: 32 q-rows x full Co=256 (acc 8x f32x16 = 128 VGPR). Block = 128q,
// 4 waves. LDS qword-padded: Ks pitch 264B / Vt pitch 72B -> 2-way max (free).
// T14 async stage split (issue global loads under compute), T5 setprio.
// ---------------------------------------------------------------------------
__global__ __launch_bounds__(256, 2)
void attn_kernel(const u8* __restrict__ kT, const u8* __restrict__ qT,
                 const u8* __restrict__ vT2, __bf16* __restrict__ Opart,
                 float* __restrict__ lbuf)
{
    const int b = blockIdx.z, part = blockIdx.y, n0 = blockIdx.x * 128;
    const int tid = threadIdx.x;
    const int wave = tid >> 6, lane = tid & 63;
    const int l32 = lane & 31, hs = lane >> 5;

    __shared__ i64t Ks8[64][33];    // [kv][c qwords], pitch 264 B (66 dw: 2-way)
    __shared__ i64t Vt8[256][9];    // [co][kv qwords, dword-interleaved], 72 B

    const int start = part * (NN / SPLIT);        // 512 kv per part
    const u8* Ksrc = qT + ((size_t)b * NN + start) * CO;   // attn-K rows [kv][c]
    const u8* Vsrc = vT2 + (size_t)b * CO * NN + start;    // [co][kv]

    // resident Q fragments (B operand): lane holds Q[q=l32][c=s*16+hs*8 ..+7]
    i64t aq[16];
    {
        const u8* qrow = kT + ((size_t)b * NN + n0 + wave * 32 + l32) * CO + hs * 8;
        #pragma unroll
        for (int s = 0; s < 16; ++s) aq[s] = *(const i64t*)(qrow + s * 16);
    }

    f32x16 acc[8];
    #pragma unroll
    for (int t = 0; t < 8; ++t)
        #pragma unroll
        for (int r = 0; r < 16; ++r) acc[t][r] = 0.f;
    float lp = 0.f;

    // T14: stage tile 0 into registers
    int4 kx[4], vx[4];
    #pragma unroll
    for (int r2 = 0; r2 < 4; ++r2) {
        int c = tid + 256 * r2;
        kx[r2] = *(const int4*)(Ksrc + (size_t)(c >> 4) * CO + (c & 15) * 16);
        vx[r2] = *(const int4*)(Vsrc + (size_t)(c >> 2) * NN + (c & 3) * 16);
    }

    for (int it = 0; it < NN / SPLIT / 64; ++it) {
        // registers -> LDS (split b64 writes; V gets middle-dword swap so that
        // row qword 2g   = kv{16g+0..3, 16g+8..11}  (PV slots 0-7,  hs=0)
        //     qword 2g+1 = kv{16g+4..7, 16g+12..15} (PV slots 8-15, hs=1)
        #pragma unroll
        for (int r2 = 0; r2 < 4; ++r2) {
            int c = tid + 256 * r2;
            i64t* kd = &Ks8[c >> 4][(c & 15) * 2];
            kd[0] = *(const i64t*)&kx[r2].x;
            kd[1] = *(const i64t*)&kx[r2].z;
            i64t* vd = &Vt8[c >> 2][(c & 3) * 2];
            vd[0] = pack64((unsigned)vx[r2].x, (unsigned)vx[r2].z);
            vd[1] = pack64((unsigned)vx[r2].y, (unsigned)vx[r2].w);
        }
        __syncthreads();

        // issue next tile's global loads; latency hides under QK^T + PV
        if (it + 1 < NN / SPLIT / 64) {
            const u8* Kit = Ksrc + (size_t)(it + 1) * 64 * CO;
            const u8* Vit = Vsrc + (it + 1) * 64;
            #pragma unroll
            for (int r2 = 0; r2 < 4; ++r2) {
                int c = tid + 256 * r2;
                kx[r2] = *(const int4*)(Kit + (size_t)(c >> 4) * CO + (c & 15) * 16);
                vx[r2] = *(const int4*)(Vit + (size_t)(c >> 2) * NN + (c & 3) * 16);
            }
        }

        // S^T = K Q^T per 32-kv subtile: D[kv][q=l32]; softmax lane-local
        int dpk[8];
        #pragma unroll
        for (int sub = 0; sub < 2; ++sub) {
            f32x16 sacc;
            #pragma unroll
            for (int r = 0; r < 16; ++r) sacc[r] = 0.f;
            __builtin_amdgcn_s_setprio(1);
            #pragma unroll
            for (int s = 0; s < 16; ++s) {
                i64t kf = Ks8[sub * 32 + l32][s * 2 + hs];
                sacc = __builtin_amdgcn_mfma_f32_32x32x16_fp8_fp8(kf, aq[s], sacc, 0, 0, 0);
            }
            __builtin_amdgcn_s_setprio(0);
            // stats-free softmax: p = exp(S/16); reg r -> kv = (r&3)+8*(r>>2)+4*hs
            #pragma unroll
            for (int r = 0; r < 16; ++r) {
                sacc[r] = __expf(sacc[r] * SCALE);
                lp += sacc[r];
            }
            #pragma unroll
            for (int g = 0; g < 4; ++g) {
                int lo = __builtin_amdgcn_cvt_pk_fp8_f32(sacc[4*g+0], sacc[4*g+1], 0, false);
                dpk[sub * 4 + g] = __builtin_amdgcn_cvt_pk_fp8_f32(sacc[4*g+2], sacc[4*g+3], lo, true);
            }
        }
        // PV A-frags: chunk c (16 kv) = {dpk[2c], dpk[2c+1]} — already slot-ordered
        i64t pa[4];
        #pragma unroll
        for (int c = 0; c < 4; ++c)
            pa[c] = pack64((unsigned)dpk[2 * c], (unsigned)dpk[2 * c + 1]);

        __builtin_amdgcn_s_setprio(1);
        #pragma unroll
        for (int t = 0; t < 8; ++t) {
            #pragma unroll
            for (int c = 0; c < 4; ++c) {
                i64t bvf = Vt8[t * 32 + l32][c * 2 + hs];
                acc[t] = __builtin_amdgcn_mfma_f32_32x32x16_fp8_fp8(pa[c], bvf, acc[t], 0, 0, 0);
            }
        }
        __builtin_amdgcn_s_setprio(0);
        __syncthreads();   // LDS reads done before next tile's writes
    }

    // row sums: lane holds half of q-row l32's kv mass; partner is lane^32
    lp += __shfl_xor(lp, 32);
    if (hs == 0)
        lbuf[(size_t)(part * NB + b) * NN + n0 + wave * 32 + l32] = lp;

    // store unnormalized bf16 partial: D[q over regs][co = t*32 + l32]
    const size_t qbase = (size_t)(part * NB + b) * NN + n0 + wave * 32;
    #pragma unroll
    for (int t = 0; t < 8; ++t)
        #pragma unroll
        for (int r = 0; r < 16; ++r) {
            int row = (r & 3) + 8 * (r >> 2) + 4 * hs;
            Opart[(qbase + row) * CO + t * 32 + l32] = (__bf16)acc[t][r];
        }
}

// ---------------------------------------------------------------------------
// up v3: merge fused into staging. out[b][ci][n] = x + sc*(b2[ci] +
// sum_cv w2[ci][cv] * Z'[cv][n]) where Z'[cv][n] = (sum_p Opart_p)/(sum_p l_p)
// viewed through the raw [B,N,Co]->[B,Co,N] reshape. For a fixed block the
// softmax row n_orig = cv*8 + (n0>>8) (constant across each 8-elem run and
// across the 128-n tile), so a 256-entry LDS invl table indexed by cv covers
// all chunks. Eliminates merge_kernel (40 MB pass + launch) and the ob buffer;
// arithmetic identical minus one bf16 round-trip.
// ---------------------------------------------------------------------------
__global__ __launch_bounds__(256)
void up_kernel(const __bf16* __restrict__ Opart, const float* __restrict__ lbuf,
               const float* __restrict__ x,
               const float* __restrict__ w2, const float* __restrict__ b2,
               const float* __restrict__ scaling, float* __restrict__ out)
{
    const int b = blockIdx.z, n0 = blockIdx.x * 128, ci0 = blockIdx.y * 128;
    const int tid = threadIdx.x;
    const int wave = tid >> 6, lane = tid & 63;
    const int l16 = lane & 15, quad = lane >> 4;
    const int wn = wave & 1, wci = wave >> 1;

    __shared__ __bf16 Zt[128][40];
    __shared__ __bf16 Wt[128][40];
    __shared__ float invl[256];

    const size_t PSTRIDE = (size_t)NB * NN * CO;            // Opart part stride
    const __bf16* Opb = Opart + (size_t)b * NN * CO;        // this batch, part 0

    // per-block denominator table: invl[cv] = 1 / sum_p l_p[cv*8 + (n0>>8)]
    {
        const int norig = tid * 8 + (n0 >> 8);
        float ls = 0.f;
        #pragma unroll
        for (int p = 0; p < SPLIT; ++p)
            ls += lbuf[(size_t)(p * NB + b) * NN + norig];
        invl[tid] = 1.0f / ls;
    }
    __syncthreads();

    f32x4 acc[4][4];
    #pragma unroll
    for (int i = 0; i < 4; ++i)
        #pragma unroll
        for (int j = 0; j < 4; ++j) acc[i][j] = f32x4{0,0,0,0};

    // Z staging coords: thread owns 8 consecutive n (one row-stripe) x 1 cv,
    // two units (cv and cv+16). Stripe zm = row>>3, thread-constant.
    const int zm = tid & 15;          // n-stripe: rows zm*8 .. zm*8+7
    const int zcv = tid >> 4;         // cv lane 0..15
    const int zsw = 8 * (zm & 3);     // XOR column swizzle (thread-constant)

    for (int k0 = 0; k0 < CO; k0 += 32) {
        #pragma unroll
        for (int u = 0; u < 2; ++u) {
            const int cv = zcv + 16 * u;
            const size_t fbase = (size_t)(k0 + cv) * NN + n0 + zm * 8;
            float s[8] = {0,0,0,0,0,0,0,0};
            #pragma unroll
            for (int p = 0; p < SPLIT; ++p) {
                v8bf v = *(const v8bf*)(Opb + (size_t)p * PSTRIDE + fbase);
                #pragma unroll
                for (int j = 0; j < 8; ++j) s[j] += (float)v[j];
            }
            const float il = invl[k0 + cv];
            const int col = cv ^ zsw;
            #pragma unroll
            for (int i = 0; i < 8; ++i)
                Zt[zm * 8 + i][col] = (__bf16)(s[i] * il);
        }
        #pragma unroll
        for (int g = 0; g < 4; ++g) {
            int f = tid + 256 * g;
            int ci = f >> 3, cq = f & 7;
            float4 v = *(const float4*)(w2 + (size_t)(ci0 + ci) * CO + k0 + cq * 4);
            *(v4bf*)&Wt[ci][cq * 4] = v4bf{(__bf16)v.x, (__bf16)v.y, (__bf16)v.z, (__bf16)v.w};
        }
        __syncthreads();
        v8bf aw[4], bz[4];
        #pragma unroll
        for (int i = 0; i < 4; ++i) aw[i] = *(const v8bf*)&Wt[wci * 64 + i * 16 + l16][quad * 8];
        #pragma unroll
        for (int j = 0; j < 4; ++j) {
            const int row = wn * 64 + j * 16 + l16;
            const int col = (quad ^ ((row >> 3) & 3)) * 8;   // inverse swizzle
            bz[j] = *(const v8bf*)&Zt[row][col];
        }
        #pragma unroll
        for (int i = 0; i < 4; ++i)
            #pragma unroll
            for (int j = 0; j < 4; ++j)
                acc[i][j] = __builtin_amdgcn_mfma_f32_16x16x32_bf16(aw[i], bz[j], acc[i][j], 0, 0, 0);
        __syncthreads();
    }
    float sc = scaling[0];
    #pragma unroll
    for (int i = 0; i < 4; ++i) {
        int ci = ci0 + wci * 64 + i * 16 + quad * 4;
        #pragma unroll
        for (int r = 0; r < 4; ++r) {
            float bvv = b2[ci + r];
            #pragma unroll
            for (int j = 0; j < 4; ++j) {
                int n = n0 + wn * 64 + j * 16 + l16;
                size_t gi = ((size_t)b * CI + ci + r) * NN + n;
                out[gi] = x[gi] + sc * (acc[i][j][r] + bvv);
            }
        }
    }
}

extern "C" void kernel_launch(void* const* d_in, const int* in_sizes, int n_in,
                              void* d_out, int out_size, void* d_ws, size_t ws_size,
                              hipStream_t stream)
{
    (void)in_sizes; (void)n_in; (void)out_size; (void)ws_size;
    const float* x       = (const float*)d_in[0];
    const float* query   = (const float*)d_in[1];
    const float* key_w   = (const float*)d_in[2];
    const float* key_b   = (const float*)d_in[3];
    const float* val_w   = (const float*)d_in[4];
    const float* val_b   = (const float*)d_in[5];
    const float* query_w = (const float*)d_in[6];
    const float* query_b = (const float*)d_in[7];
    const float* up_w    = (const float*)d_in[8];
    const float* up_b    = (const float*)d_in[9];
    const float* scaling = (const float*)d_in[10];
    float* out = (float*)d_out;

    const size_t TEN = (size_t)NB * NN * CO;   // 4,194,304 elements
    u8* kT  = (u8*)d_ws;                       // [B,N,Co] fp8 (key proj = attn Q)
    u8* qT  = kT + TEN;                        // [B,N,Co] fp8 (query proj = attn K)
    u8* vT2 = qT + TEN;                        // [B,Co,N] fp8
    __bf16* Opart = (__bf16*)(vT2 + TEN);      // [SPLIT,B,N,Co] bf16
    float*  lbuf  = (float*)(Opart + (size_t)SPLIT * TEN);  // [SPLIT,B,N]

    dim3 blk(256);
    proj3_kernel<<<dim3(NN / 128, CO / 64, NB), blk, 0, stream>>>(
        x, query, key_w, key_b, val_w, val_b, query_w, query_b, kT, vT2, qT);
    attn_kernel<<<dim3(NN / 128, SPLIT, NB), blk, 0, stream>>>(kT, qT, vT2, Opart, lbuf);
    up_kernel<<<dim3(NN / 128, CI / 128, NB), blk, 0, stream>>>(
        Opart, lbuf, x, up_w, up_b, scaling, out);
}